// Round 11
// baseline (185.187 us; speedup 1.0000x reference)
//
#include <hip/hip_runtime.h>

// GraphConstruction: x[1,1024,1024] fp32 -> A[4096,4096] in {0,1} fp32.
// patches[n,r,k] = x[h,w], h = (n&15)*64 + (r>>2)*16 + (n>>8),
//                          w = (r&3)*256 + k*16 + ((n>>4)&15)
// LOCKED NUMERICS (R6/R7/R9/R10, absmax 0):
//   sq[n,k]: acc = p0^2; acc = acc + fl(p_r^2), r ascending (plain adds)
//   G: acc = fmaf(a_r, b_r, acc), r ascending;  d2 = fmaf(-2,G,fl(si+sj))
//   decision: all_k (d2 <= 49.0f);  A bit-exactly symmetric -> mirror stores.
// R11: 8x4 thread tile, 128 threads (R10 calibrated model: LDS-read-pipe
//      bound, compute reads = 79% of pipe; (u+v)/rc per lane is the knob).
//      Compute reads/block 2048 -> 1536. Live regs ~105 < the measured
//      128-live spill cliff (R8/R9). launch_bounds(128,2), LDS 17.4 KB.

#define NPATCH 4096
#define BT 64
#define KC 2
#define NPH 8

__global__ __launch_bounds__(128, 2) void adj_kernel(const float* __restrict__ x,
                                                     float* __restrict__ A) {
#pragma clang fp contract(off)
    // Row = 8 float4 chunks, chunk c = kl*4+rc stored at c^((row>>2)&7),
    // elem = r&3. a-reads broadcast; b-reads 2-way; staging writes ~2-way.
    __shared__ float4 Si[BT][8];
    __shared__ float4 Sj[BT][8];
    __shared__ float sqs[2][KC][BT];

    // linear -> lower-triangle (bi >= bj)
    int t = blockIdx.x;
    int bi = (int)((sqrtf(8.0f * (float)t + 1.0f) - 1.0f) * 0.5f);
    while ((bi + 1) * (bi + 2) / 2 <= t) ++bi;
    while (bi * (bi + 1) / 2 > t) --bi;
    int bj = t - bi * (bi + 1) / 2;

    const int i0 = bi * BT;
    const int j0 = bj * BT;
    const int tid = threadIdx.x;
    const int tx = tid & 15;       // j-cols tx*4..+3
    const int ty = tid >> 4;       // i-rows ty*8..+7  (0..7)

    unsigned int bad = 0u;         // bit u*4+v set => some d2 > 49

    for (int kp = 0; kp < NPH; ++kp) {
        __syncthreads();
        // ---- stage: 1024 float4 loads, 8/thread; load covers rows {16*dd+rl} ----
#pragma unroll
        for (int l = 0; l < 8; ++l) {
            int gid = l * 128 + tid;
            int side = gid >> 9;
            int q = gid & 511;             // kl(1) | r(4) | rl(4)
            int kl = q & 1;
            int r = (q >> 1) & 15;
            int rl = q >> 5;
            int k = kp * KC + kl;
            int b = side ? bj : bi;
            int h = rl * 64 + (r >> 2) * 16 + (b >> 2);
            int w0 = (r & 3) * 256 + k * 16 + ((4 * b) & 15);
            float4 v = *(const float4*)&x[h * 1024 + w0];
            const float* vp = (const float*)&v;
            int c = (kl << 2) | (r >> 2);
            int e = r & 3;
            float4* Sb = side ? &Sj[0][0] : &Si[0][0];
#pragma unroll
            for (int dd = 0; dd < 4; ++dd) {   // elem dd -> row 16*dd+rl
                int row = 16 * dd + rl;
                int ch = c ^ ((row >> 2) & 7);
                ((float*)&Sb[row * 8 + ch])[e] = vp[dd];
            }
        }
        __syncthreads();
        // ---- per-column sq: plain adds, r ascending (2 tasks/thread) ----
#pragma unroll
        for (int p = 0; p < 2; ++p) {
            int s0 = p * 128 + tid;
            int side = s0 >> 7;
            int kl = (s0 >> 6) & 1;
            int row = s0 & 63;
            const float4* Sb = side ? &Sj[row][0] : &Si[row][0];
            int swz = (row >> 2) & 7;
            float acc;
            {
                float4 v = Sb[(kl * 4) ^ swz];
                acc = v.x * v.x;
                float t1 = v.y * v.y; acc = acc + t1;
                float t2 = v.z * v.z; acc = acc + t2;
                float t3 = v.w * v.w; acc = acc + t3;
            }
#pragma unroll
            for (int rc = 1; rc < 4; ++rc) {
                float4 v = Sb[(kl * 4 + rc) ^ swz];
                float t0 = v.x * v.x; acc = acc + t0;
                float t1 = v.y * v.y; acc = acc + t1;
                float t2 = v.z * v.z; acc = acc + t2;
                float t3 = v.w * v.w; acc = acc + t3;
            }
            sqs[side][kl][row] = acc;
        }
        __syncthreads();
        // ---- compute: 8x4 cells, fmaf chains r ascending ----
#pragma unroll
        for (int kl = 0; kl < KC; ++kl) {
            float d[8][4];
#pragma unroll
            for (int u = 0; u < 8; ++u)
#pragma unroll
                for (int v = 0; v < 4; ++v) d[u][v] = 0.0f;
#pragma unroll
            for (int rc = 0; rc < 4; ++rc) {
                int c = kl * 4 + rc;
                float4 a[8], b[4];
#pragma unroll
                for (int u = 0; u < 8; ++u)
                    a[u] = Si[ty * 8 + u][c ^ ((2 * ty + (u >> 2)) & 7)];
#pragma unroll
                for (int v = 0; v < 4; ++v)
                    b[v] = Sj[tx * 4 + v][c ^ (tx & 7)];
#pragma unroll
                for (int u = 0; u < 8; ++u)
#pragma unroll
                    for (int v = 0; v < 4; ++v) {
                        d[u][v] = fmaf(a[u].x, b[v].x, d[u][v]);
                        d[u][v] = fmaf(a[u].y, b[v].y, d[u][v]);
                        d[u][v] = fmaf(a[u].z, b[v].z, d[u][v]);
                        d[u][v] = fmaf(a[u].w, b[v].w, d[u][v]);
                    }
            }
#pragma unroll
            for (int u = 0; u < 8; ++u) {
                float si = sqs[0][kl][ty * 8 + u];
#pragma unroll
                for (int v = 0; v < 4; ++v) {
                    float sj = sqs[1][kl][tx * 4 + v];
                    float s = si + sj;                    // fl(si+sj)
                    float d2 = fmaf(-2.0f, d[u][v], s);   // fl(s-2G)
                    bad |= (d2 > 49.0f) ? (1u << (u * 4 + v)) : 0u;
                }
            }
        }
    }

    // ---- stores: direct + mirrored (A exactly symmetric) ----
#pragma unroll
    for (int u = 0; u < 8; ++u) {
        float4 o;
        o.x = (bad >> (u * 4 + 0)) & 1u ? 0.0f : 1.0f;
        o.y = (bad >> (u * 4 + 1)) & 1u ? 0.0f : 1.0f;
        o.z = (bad >> (u * 4 + 2)) & 1u ? 0.0f : 1.0f;
        o.w = (bad >> (u * 4 + 3)) & 1u ? 0.0f : 1.0f;
        *(float4*)&A[(size_t)(i0 + ty * 8 + u) * NPATCH + j0 + tx * 4] = o;
    }
    if (bi != bj) {
#pragma unroll
        for (int v = 0; v < 4; ++v) {
#pragma unroll
            for (int g = 0; g < 2; ++g) {
                float4 o;
                o.x = (bad >> ((g * 4 + 0) * 4 + v)) & 1u ? 0.0f : 1.0f;
                o.y = (bad >> ((g * 4 + 1) * 4 + v)) & 1u ? 0.0f : 1.0f;
                o.z = (bad >> ((g * 4 + 2) * 4 + v)) & 1u ? 0.0f : 1.0f;
                o.w = (bad >> ((g * 4 + 3) * 4 + v)) & 1u ? 0.0f : 1.0f;
                *(float4*)&A[(size_t)(j0 + tx * 4 + v) * NPATCH + i0 + ty * 8 + g * 4] = o;
            }
        }
    }
}

extern "C" void kernel_launch(void* const* d_in, const int* in_sizes, int n_in,
                              void* d_out, int out_size, void* d_ws, size_t ws_size,
                              hipStream_t stream) {
    const float* x = (const float*)d_in[0];
    float* A = (float*)d_out;
    (void)d_ws; (void)ws_size;

    const int nblk = (NPATCH / BT) * (NPATCH / BT + 1) / 2;  // 2080
    adj_kernel<<<nblk, 128, 0, stream>>>(x, A);
}

// Round 12
// 181.955 us; speedup vs baseline: 1.0178x; 1.0178x over previous
//
#include <hip/hip_runtime.h>

// GraphConstruction: x[1,1024,1024] fp32 -> A[4096,4096] in {0,1} fp32.
// patches[n,r,k] = x[h,w], h = (n&15)*64 + (r>>2)*16 + (n>>8),
//                          w = (r&3)*256 + k*16 + ((n>>4)&15)
// LOCKED NUMERICS (R6..R11, absmax 0):
//   sq[n,k]: acc = p0^2; acc = acc + fl(p_r^2), r ascending (plain adds)
//   G: acc = fmaf(a_r, b_r, acc), r ascending;  d2 = fmaf(-2,G,fl(si+sj))
//   decision: all_k (d2 <= 49.0f);  A bit-exactly symmetric -> mirror stores.
// R12: R11's 8x4 read ratio was right but 128-thread blocks went
//      latency-bound (VALUBusy 42%, ~5 waves/CU). Fix: 256 threads,
//      128x64 block tile (16x16 thread grid, 8x4/thread). Grid: 128-row
//      strips bi<32, 64-col strips bj<=2bi+1 -> 1056 blocks; mirror covers
//      the rest (diag-tile overlaps write bit-identical values - benign).
//      LDS ~25.5 KB -> 6 blocks/CU; VGPR ~112 -> 4 waves/EU.

#define NPATCH 4096
#define KC 2
#define NPH 8

__global__ __launch_bounds__(256, 2) void adj_kernel(const float* __restrict__ x,
                                                     float* __restrict__ A) {
#pragma clang fp contract(off)
    // Row = 8 float4 chunks, chunk c = kl*4+rc stored at c^((row>>2)&7),
    // elem = r&3. a-reads broadcast; b-reads 2-way; staging writes 2-way.
    __shared__ float4 Si[128][8];
    __shared__ float4 Sj[64][8];
    __shared__ float sqi[KC][128];
    __shared__ float sqj[KC][64];

    // linear t -> (bi, bj): blocks with bj in [0, 2*bi+2), prefix = bi^2+bi
    int t = blockIdx.x;
    int bi = (int)((sqrtf(4.0f * (float)t + 1.0f) - 1.0f) * 0.5f);
    while ((bi + 1) * (bi + 2) > t) --bi;          // want bi^2+bi <= t
    while ((bi + 1) * (bi + 2) <= t) ++bi;
    int bj = t - bi * (bi + 1);

    const int i0 = bi * 128;
    const int j0 = bj * 64;
    const int tid = threadIdx.x;
    const int tx = tid & 15;       // j-cols tx*4..+3
    const int ty = tid >> 4;       // i-rows ty*8..+7  (0..15)

    unsigned int bad = 0u;         // bit u*4+v set => some d2 > 49

    for (int kp = 0; kp < NPH; ++kp) {
        __syncthreads();
        // ---- stage: 1536 float4 loads, 6/thread; strips {2bi, 2bi+1, bj} ----
#pragma unroll
        for (int l = 0; l < 6; ++l) {
            int gid = l * 256 + tid;
            int strip = gid >> 9;              // 0: iA, 1: iB, 2: j
            int q = gid & 511;                 // kl(1) | r(4) | rl(4)
            int kl = q & 1;
            int r = (q >> 1) & 15;
            int rl = q >> 5;
            int k = kp * KC + kl;
            int b = (strip == 2) ? bj : (2 * bi + strip);
            int h = rl * 64 + (r >> 2) * 16 + (b >> 2);
            int w0 = (r & 3) * 256 + k * 16 + ((4 * b) & 15);
            float4 v = *(const float4*)&x[h * 1024 + w0];
            const float* vp = (const float*)&v;
            int c = (kl << 2) | (r >> 2);
            int e = r & 3;
            float4* Sb = (strip == 2) ? &Sj[0][0] : &Si[(strip == 1) ? 64 : 0][0];
#pragma unroll
            for (int dd = 0; dd < 4; ++dd) {   // elem dd -> row 16*dd+rl
                int row = 16 * dd + rl;
                int ch = c ^ ((row >> 2) & 7); // (row+64)>>2 &7 == row>>2 &7
                ((float*)&Sb[row * 8 + ch])[e] = vp[dd];
            }
        }
        __syncthreads();
        // ---- per-column sq: plain adds, r ascending (384 tasks) ----
        for (int s0 = tid; s0 < 384; s0 += 256) {
            int sideJ = (s0 >= 256);
            int row, kl;
            const float4* Sb;
            float* dst;
            if (!sideJ) { row = s0 & 127; kl = s0 >> 7; Sb = &Si[row][0]; dst = &sqi[kl][row]; }
            else { int q = s0 - 256; row = q & 63; kl = q >> 6; Sb = &Sj[row][0]; dst = &sqj[kl][row]; }
            int swz = (row >> 2) & 7;
            float acc;
            {
                float4 v = Sb[(kl * 4) ^ swz];
                acc = v.x * v.x;
                float t1 = v.y * v.y; acc = acc + t1;
                float t2 = v.z * v.z; acc = acc + t2;
                float t3 = v.w * v.w; acc = acc + t3;
            }
#pragma unroll
            for (int rc = 1; rc < 4; ++rc) {
                float4 v = Sb[(kl * 4 + rc) ^ swz];
                float t0 = v.x * v.x; acc = acc + t0;
                float t1 = v.y * v.y; acc = acc + t1;
                float t2 = v.z * v.z; acc = acc + t2;
                float t3 = v.w * v.w; acc = acc + t3;
            }
            *dst = acc;
        }
        __syncthreads();
        // ---- compute: 8x4 cells, fmaf chains r ascending ----
#pragma unroll
        for (int kl = 0; kl < KC; ++kl) {
            float d[8][4];
#pragma unroll
            for (int u = 0; u < 8; ++u)
#pragma unroll
                for (int v = 0; v < 4; ++v) d[u][v] = 0.0f;
#pragma unroll
            for (int rc = 0; rc < 4; ++rc) {
                int c = kl * 4 + rc;
                float4 a[8], b[4];
#pragma unroll
                for (int u = 0; u < 8; ++u)
                    a[u] = Si[ty * 8 + u][c ^ ((2 * ty + (u >> 2)) & 7)];
#pragma unroll
                for (int v = 0; v < 4; ++v)
                    b[v] = Sj[tx * 4 + v][c ^ (tx & 7)];
#pragma unroll
                for (int u = 0; u < 8; ++u)
#pragma unroll
                    for (int v = 0; v < 4; ++v) {
                        d[u][v] = fmaf(a[u].x, b[v].x, d[u][v]);
                        d[u][v] = fmaf(a[u].y, b[v].y, d[u][v]);
                        d[u][v] = fmaf(a[u].z, b[v].z, d[u][v]);
                        d[u][v] = fmaf(a[u].w, b[v].w, d[u][v]);
                    }
            }
#pragma unroll
            for (int u = 0; u < 8; ++u) {
                float si = sqi[kl][ty * 8 + u];
#pragma unroll
                for (int v = 0; v < 4; ++v) {
                    float sj = sqj[kl][tx * 4 + v];
                    float s = si + sj;                    // fl(si+sj)
                    float d2 = fmaf(-2.0f, d[u][v], s);   // fl(s-2G)
                    bad |= (d2 > 49.0f) ? (1u << (u * 4 + v)) : 0u;
                }
            }
        }
    }

    // ---- stores: direct + mirrored (A exactly symmetric; overlaps are
    //      bit-identical on diagonal-straddling tiles) ----
#pragma unroll
    for (int u = 0; u < 8; ++u) {
        float4 o;
        o.x = (bad >> (u * 4 + 0)) & 1u ? 0.0f : 1.0f;
        o.y = (bad >> (u * 4 + 1)) & 1u ? 0.0f : 1.0f;
        o.z = (bad >> (u * 4 + 2)) & 1u ? 0.0f : 1.0f;
        o.w = (bad >> (u * 4 + 3)) & 1u ? 0.0f : 1.0f;
        *(float4*)&A[(size_t)(i0 + ty * 8 + u) * NPATCH + j0 + tx * 4] = o;
    }
#pragma unroll
    for (int v = 0; v < 4; ++v) {
#pragma unroll
        for (int g = 0; g < 2; ++g) {
            float4 o;
            o.x = (bad >> ((g * 4 + 0) * 4 + v)) & 1u ? 0.0f : 1.0f;
            o.y = (bad >> ((g * 4 + 1) * 4 + v)) & 1u ? 0.0f : 1.0f;
            o.z = (bad >> ((g * 4 + 2) * 4 + v)) & 1u ? 0.0f : 1.0f;
            o.w = (bad >> ((g * 4 + 3) * 4 + v)) & 1u ? 0.0f : 1.0f;
            *(float4*)&A[(size_t)(j0 + tx * 4 + v) * NPATCH + i0 + ty * 8 + g * 4] = o;
        }
    }
}

extern "C" void kernel_launch(void* const* d_in, const int* in_sizes, int n_in,
                              void* d_out, int out_size, void* d_ws, size_t ws_size,
                              hipStream_t stream) {
    const float* x = (const float*)d_in[0];
    float* A = (float*)d_out;
    (void)d_ws; (void)ws_size;

    const int nblk = 32 * 33;  // sum of (2*bi+2), bi=0..31 -> 1056
    adj_kernel<<<nblk, 256, 0, stream>>>(x, A);
}

// Round 13
// 153.972 us; speedup vs baseline: 1.2027x; 1.1817x over previous
//
#include <hip/hip_runtime.h>

// GraphConstruction: x[1,1024,1024] fp32 -> A[4096,4096] in {0,1} fp32.
// patches[n,r,k] = x[h,w], h = (n&15)*64 + (r>>2)*16 + (n>>8),
//                          w = (r&3)*256 + k*16 + ((n>>4)&15)
// LOCKED NUMERICS (R6..R12, absmax 0):
//   sq[n,k]: acc = p0^2; acc = acc + fl(p_r^2), r ascending (plain adds)
//   G: acc = fmaf(a_r, b_r, acc), r ascending;  d2 = fmaf(-2,G,fl(si+sj))
//   decision: all_k (d2 <= 49.0f);  A bit-exactly symmetric -> mirror stores.
// R13 = R10 + bank-conflict fix. R11/R12 lesson: 8x4 tile costs 112-128 VGPR
//   -> 4 waves/EU (half of R10's 8) -> latency-bound at 134us. Stay 4x4/64reg.
//   R10's 9.6M conflict cycles: row stride 128B == 0 mod 32 banks, so bank
//   group = chunk only (8 groups); lanes tx,tx+8 share c^(tx&7) -> 2-way on
//   every b-read. Fix: stride 9 float4 (group = (row+slot)%8) + swz(row) =
//   ((row>>2)+(row>>5))&7 (rows 32 apart differ -> tx,tx+8 split groups).

#define NPATCH 4096
#define BT 64
#define KC 2
#define NPH 8
#define RSTRIDE 9   // float4 per row (8 data + 1 pad)

__device__ __forceinline__ int swzrow(int row) {
    return ((row >> 2) + (row >> 5)) & 7;
}

__global__ __launch_bounds__(256, 3) void adj_kernel(const float* __restrict__ x,
                                                     float* __restrict__ A) {
#pragma clang fp contract(off)
    __shared__ float4 Si[BT * RSTRIDE];
    __shared__ float4 Sj[BT * RSTRIDE];
    __shared__ float sqs[2][KC][BT];

    // linear -> lower-triangle (bi >= bj)
    int t = blockIdx.x;
    int bi = (int)((sqrtf(8.0f * (float)t + 1.0f) - 1.0f) * 0.5f);
    while ((bi + 1) * (bi + 2) / 2 <= t) ++bi;
    while (bi * (bi + 1) / 2 > t) --bi;
    int bj = t - bi * (bi + 1) / 2;

    const int i0 = bi * BT;
    const int j0 = bj * BT;
    const int tid = threadIdx.x;
    const int tx = tid & 15;       // j-cols tx*4..+3
    const int ty = tid >> 4;       // i-rows ty*4..+3
    const int swzA = (ty + (ty >> 3)) & 7;   // == swzrow(ty*4+u) for u<4
    const int swzB = (tx + (tx >> 3)) & 7;   // == swzrow(tx*4+v) for v<4

    float m[4][4];
#pragma unroll
    for (int u = 0; u < 4; ++u)
#pragma unroll
        for (int v = 0; v < 4; ++v) m[u][v] = -3.0e38f;

    for (int kp = 0; kp < NPH; ++kp) {
        __syncthreads();
        // ---- stage: 1024 float4 loads, 4/thread; load covers rows {16*dd+rl} ----
#pragma unroll
        for (int l = 0; l < 4; ++l) {
            int gid = l * 256 + tid;
            int side = gid >> 9;
            int q = gid & 511;             // kl(1) | r(4) | rl(4)
            int kl = q & 1;
            int r = (q >> 1) & 15;
            int rl = q >> 5;
            int k = kp * KC + kl;
            int b = side ? bj : bi;
            int h = rl * 64 + (r >> 2) * 16 + (b >> 2);
            int w0 = (r & 3) * 256 + k * 16 + ((4 * b) & 15);
            float4 v = *(const float4*)&x[h * 1024 + w0];
            const float* vp = (const float*)&v;
            int c = (kl << 2) | (r >> 2);
            int e = r & 3;
            float* Sb = side ? (float*)Sj : (float*)Si;
#pragma unroll
            for (int dd = 0; dd < 4; ++dd) {   // elem dd -> row 16*dd+rl
                int row = 16 * dd + rl;
                int ch = c ^ swzrow(row);
                Sb[(row * RSTRIDE + ch) * 4 + e] = vp[dd];
            }
        }
        __syncthreads();
        // ---- per-column sq: plain adds, r ascending (1 value/thread) ----
        {
            int side = tid >> 7;
            int kl = (tid >> 6) & 1;
            int row = tid & 63;
            const float4* Sb = (side ? Sj : Si) + row * RSTRIDE;
            int swz = swzrow(row);
            float acc;
            {
                float4 v = Sb[(kl * 4) ^ swz];
                acc = v.x * v.x;
                float t1 = v.y * v.y; acc = acc + t1;
                float t2 = v.z * v.z; acc = acc + t2;
                float t3 = v.w * v.w; acc = acc + t3;
            }
#pragma unroll
            for (int rc = 1; rc < 4; ++rc) {
                float4 v = Sb[(kl * 4 + rc) ^ swz];
                float t0 = v.x * v.x; acc = acc + t0;
                float t1 = v.y * v.y; acc = acc + t1;
                float t2 = v.z * v.z; acc = acc + t2;
                float t3 = v.w * v.w; acc = acc + t3;
            }
            sqs[side][kl][row] = acc;
        }
        __syncthreads();
        // ---- compute: 4x4 cells, fmaf chains r ascending ----
#pragma unroll
        for (int kl = 0; kl < KC; ++kl) {
            float d[4][4];
#pragma unroll
            for (int u = 0; u < 4; ++u)
#pragma unroll
                for (int v = 0; v < 4; ++v) d[u][v] = 0.0f;
#pragma unroll
            for (int rc = 0; rc < 4; ++rc) {
                int c = kl * 4 + rc;
                float4 a[4], b[4];
#pragma unroll
                for (int u = 0; u < 4; ++u)
                    a[u] = Si[(ty * 4 + u) * RSTRIDE + (c ^ swzA)];
#pragma unroll
                for (int v = 0; v < 4; ++v)
                    b[v] = Sj[(tx * 4 + v) * RSTRIDE + (c ^ swzB)];
#pragma unroll
                for (int u = 0; u < 4; ++u)
#pragma unroll
                    for (int v = 0; v < 4; ++v) {
                        d[u][v] = fmaf(a[u].x, b[v].x, d[u][v]);
                        d[u][v] = fmaf(a[u].y, b[v].y, d[u][v]);
                        d[u][v] = fmaf(a[u].z, b[v].z, d[u][v]);
                        d[u][v] = fmaf(a[u].w, b[v].w, d[u][v]);
                    }
            }
            float4 si4 = *(const float4*)&sqs[0][kl][ty * 4];
            float4 sj4 = *(const float4*)&sqs[1][kl][tx * 4];
            const float* sip = (const float*)&si4;
            const float* sjp = (const float*)&sj4;
#pragma unroll
            for (int u = 0; u < 4; ++u)
#pragma unroll
                for (int v = 0; v < 4; ++v) {
                    float s = sip[u] + sjp[v];            // fl(si+sj)
                    float d2 = fmaf(-2.0f, d[u][v], s);   // fl(s-2G)
                    m[u][v] = fmaxf(m[u][v], d2);
                }
        }
    }

    // ---- stores: direct + mirrored (A exactly symmetric) ----
#pragma unroll
    for (int u = 0; u < 4; ++u) {
        float4 o;
        o.x = (m[u][0] <= 49.0f) ? 1.0f : 0.0f;
        o.y = (m[u][1] <= 49.0f) ? 1.0f : 0.0f;
        o.z = (m[u][2] <= 49.0f) ? 1.0f : 0.0f;
        o.w = (m[u][3] <= 49.0f) ? 1.0f : 0.0f;
        *(float4*)&A[(size_t)(i0 + ty * 4 + u) * NPATCH + j0 + tx * 4] = o;
    }
    if (bi != bj) {
#pragma unroll
        for (int v = 0; v < 4; ++v) {
            float4 o;
            o.x = (m[0][v] <= 49.0f) ? 1.0f : 0.0f;
            o.y = (m[1][v] <= 49.0f) ? 1.0f : 0.0f;
            o.z = (m[2][v] <= 49.0f) ? 1.0f : 0.0f;
            o.w = (m[3][v] <= 49.0f) ? 1.0f : 0.0f;
            *(float4*)&A[(size_t)(j0 + tx * 4 + v) * NPATCH + i0 + ty * 4] = o;
        }
    }
}

extern "C" void kernel_launch(void* const* d_in, const int* in_sizes, int n_in,
                              void* d_out, int out_size, void* d_ws, size_t ws_size,
                              hipStream_t stream) {
    const float* x = (const float*)d_in[0];
    float* A = (float*)d_out;
    (void)d_ws; (void)ws_size;

    const int nblk = (NPATCH / BT) * (NPATCH / BT + 1) / 2;  // 2080
    adj_kernel<<<nblk, 256, 0, stream>>>(x, A);
}